// Round 1
// baseline (543.175 us; speedup 1.0000x reference)
//
#include <hip/hip_runtime.h>
#include <stdint.h>

#define B_    16
#define N_    2500
#define K_    16
#define NIN_  64
#define NMED_ 64
#define WIN_  32
#define WMED_ 32

// ---------- helpers ----------
__device__ __forceinline__ unsigned pack_bf16(float a, float b) {
  unsigned ua = __float_as_uint(a), ub = __float_as_uint(b);
  ua = (ua + 0x7fffu + ((ua >> 16) & 1u)) >> 16;          // low  short = a
  ub = (ub + 0x7fffu + ((ub >> 16) & 1u)) & 0xffff0000u;  // high short = b
  return ua | ub;
}

__device__ __forceinline__ void unpack8(uint4 w, float* f) {
  f[0] = __uint_as_float(w.x << 16);
  f[1] = __uint_as_float(w.x & 0xffff0000u);
  f[2] = __uint_as_float(w.y << 16);
  f[3] = __uint_as_float(w.y & 0xffff0000u);
  f[4] = __uint_as_float(w.z << 16);
  f[5] = __uint_as_float(w.z & 0xffff0000u);
  f[6] = __uint_as_float(w.w << 16);
  f[7] = __uint_as_float(w.w & 0xffff0000u);
}

// ---------- kernel A: nf1 = relu(bn(nW1 @ node)), stored transposed [b*N+n][c] ----------
__global__ __launch_bounds__(256) void k_nf1(
    const float* __restrict__ node, const float* __restrict__ W,
    const float* __restrict__ bia, const float* __restrict__ sc,
    const float* __restrict__ sh, float* __restrict__ nf1) {
  int tid = blockIdx.x * 256 + threadIdx.x;   // 640,000 threads exactly
  int og  = tid & 15;                         // output quad group (16)
  int bn  = tid >> 4;                         // b*N + n  (40,000)
  int b = bn / N_;
  int n = bn - b * N_;
  const float* xp = node + (size_t)(b * 64) * N_ + n;
  int o0 = og * 4;
  const float* w0 = W + (size_t)(o0 + 0) * 64;
  const float* w1 = W + (size_t)(o0 + 1) * 64;
  const float* w2 = W + (size_t)(o0 + 2) * 64;
  const float* w3 = W + (size_t)(o0 + 3) * 64;
  float a0 = 0.f, a1 = 0.f, a2 = 0.f, a3 = 0.f;
#pragma unroll 8
  for (int c = 0; c < 64; ++c) {
    float x = xp[(size_t)c * N_];
    a0 = fmaf(w0[c], x, a0);
    a1 = fmaf(w1[c], x, a1);
    a2 = fmaf(w2[c], x, a2);
    a3 = fmaf(w3[c], x, a3);
  }
  float4 r;
  r.x = fmaxf(fmaf(sc[o0 + 0], a0 + bia[o0 + 0], sh[o0 + 0]), 0.f);
  r.y = fmaxf(fmaf(sc[o0 + 1], a1 + bia[o0 + 1], sh[o0 + 1]), 0.f);
  r.z = fmaxf(fmaf(sc[o0 + 2], a2 + bia[o0 + 2], sh[o0 + 2]), 0.f);
  r.w = fmaxf(fmaf(sc[o0 + 3], a3 + bia[o0 + 3], sh[o0 + 3]), 0.f);
  *(float4*)&nf1[(size_t)bn * 64 + o0] = r;
}

// ---------- kernel B: fused message passing + output convs + residuals ----------
// 512 threads = 8 waves; one node per wave per iteration; 4 iterations.
// grid 1250 * 32 nodes = 40,000 exactly.
__global__ __launch_bounds__(512) void k_fused(
    const float* __restrict__ node, const float* __restrict__ wfeat,
    const int* __restrict__ etype, const int* __restrict__ nn_idx,
    const float* __restrict__ nf1,
    const float* __restrict__ wW1, const float* __restrict__ wb1,
    const float* __restrict__ ws1, const float* __restrict__ wsh1,
    const float* __restrict__ theta, const float* __restrict__ theta_b,
    const float* __restrict__ gateW, const float* __restrict__ gate_b,
    const float* __restrict__ edgeW, const float* __restrict__ edge_b,
    const float* __restrict__ nW2, const float* __restrict__ nb2,
    const float* __restrict__ ns2, const float* __restrict__ nsh2,
    const float* __restrict__ wW2, const float* __restrict__ wb2,
    const float* __restrict__ ws2, const float* __restrict__ wsh2,
    float* __restrict__ out_nf, float* __restrict__ out_wf) {

  // weights (shared, staged once per block). theta/nW2/wW1/wW2 bf16-packed.
  __shared__ __align__(16) unsigned theta_s[192 * 36];  // row (t*64+o), 64 el pad->72 shorts
  __shared__ __align__(16) unsigned nW2_s[64 * 36];
  __shared__ __align__(16) unsigned wW1_s[32 * 20];
  __shared__ __align__(16) unsigned wW2_s[32 * 20];
  __shared__ __align__(16) float gateW_s[64 * 36];      // f32, row pad 36
  __shared__ __align__(16) float edgeW_s[32 * 100];     // f32, row pad 100
  __shared__ float theta_b_s[192];
  // per-wave data tiles
  __shared__ __align__(16) float x_s[8][32][16];   // x tile, later reused as w_out tile
  __shared__ __align__(16) float wf1_s[8][32][16];
  __shared__ __align__(16) float nb_s[8][64][20];
  __shared__ __align__(16) float nout_s[8][64];
  __shared__ int et_s[8][16];

  const int tid = threadIdx.x;

  // ---- stage weights into LDS ----
  for (int p = tid; p < 6144; p += 512)  // theta 3*64*64 / 2
    theta_s[(p >> 5) * 36 + (p & 31)] = pack_bf16(theta[2 * p], theta[2 * p + 1]);
  for (int p = tid; p < 2048; p += 512)  // nW2 64*64 / 2
    nW2_s[(p >> 5) * 36 + (p & 31)] = pack_bf16(nW2[2 * p], nW2[2 * p + 1]);
  for (int p = tid; p < 512; p += 512)   // wW1 32*32 / 2
    wW1_s[(p >> 4) * 20 + (p & 15)] = pack_bf16(wW1[2 * p], wW1[2 * p + 1]);
  for (int p = tid; p < 512; p += 512)
    wW2_s[(p >> 4) * 20 + (p & 15)] = pack_bf16(wW2[2 * p], wW2[2 * p + 1]);
  for (int p = tid; p < 2048; p += 512)
    gateW_s[(p >> 5) * 36 + (p & 31)] = gateW[p];
  for (int p = tid; p < 3072; p += 512)
    edgeW_s[(p / 96) * 100 + (p % 96)] = edgeW[p];
  if (tid < 192) theta_b_s[tid] = theta_b[tid];
  __syncthreads();

  const int l   = tid & 63;
  const int wv  = tid >> 6;
  const int o32 = l & 31;
  const int eh  = l >> 5;  // edge half (0: k 0-7, 1: k 8-15)

  // per-lane epilogue params (node-independent)
  const float wb1r = wb1[o32], ws1r = ws1[o32], wsh1r = wsh1[o32];
  const float gbr  = gate_b[l];
  const float nb2r = nb2[l], ns2r = ns2[l], nsh2r = nsh2[l];
  const float ebr  = edge_b[o32];
  const float wb2r = wb2[o32], ws2r = ws2[o32], wsh2r = wsh2[o32];

  for (int it = 0; it < 4; ++it) {
    const int nodeid = blockIdx.x * 32 + it * 8 + wv;  // < 40000 always
    const int b = nodeid / N_;
    const int n = nodeid - b * N_;
    const int ebase = nodeid * 16;

    // ---- load x tile (wfeat: 32 ch x 16 k) into x_s[wv][i][k] ----
#pragma unroll
    for (int r = 0; r < 2; ++r) {
      int q = r * 64 + l;
      int i = q >> 2, qe = q & 3;
      float4 v = *(const float4*)&wfeat[((size_t)(b * 32 + i) * N_ + n) * 16 + qe * 4];
      *(float4*)&x_s[wv][i][qe * 4] = v;
    }
    // ---- etype ----
    if (l < 16) et_s[wv][l] = etype[ebase + l];
    // ---- gather nb: nb_s[wv][c][k] = nf1[b, nn_idx[k]][c] (coalesced per k) ----
#pragma unroll
    for (int k = 0; k < 16; ++k) {
      int idx = nn_idx[ebase + k];
      nb_s[wv][l][k] = nf1[((size_t)b * N_ + idx) * 64 + l];
    }

    // ---- wf1 = relu(bn(wW1 @ x)); lane (o32, eh) computes 8 edges ----
    {
      float acc[8] = {0, 0, 0, 0, 0, 0, 0, 0};
      for (int oct = 0; oct < 4; ++oct) {
        uint4 wq = *(const uint4*)&wW1_s[o32 * 20 + oct * 4];
        float wf[8];
        unpack8(wq, wf);
#pragma unroll
        for (int j = 0; j < 8; ++j) {
          const float4* xr = (const float4*)&x_s[wv][oct * 8 + j][eh * 8];
          float4 p0 = xr[0], p1 = xr[1];
          float xv[8] = {p0.x, p0.y, p0.z, p0.w, p1.x, p1.y, p1.z, p1.w};
#pragma unroll
          for (int e = 0; e < 8; ++e) acc[e] = fmaf(wf[j], xv[e], acc[e]);
        }
      }
      float wa[8];
#pragma unroll
      for (int e = 0; e < 8; ++e)
        wa[e] = fmaxf(fmaf(ws1r, acc[e] + wb1r, wsh1r), 0.f);
      float4 q0 = {wa[0], wa[1], wa[2], wa[3]};
      float4 q1 = {wa[4], wa[5], wa[6], wa[7]};
      *(float4*)&wf1_s[wv][o32][eh * 8]     = q0;
      *(float4*)&wf1_s[wv][o32][eh * 8 + 4] = q1;
    }

    // ---- msg (3-acc over etypes) + gate + mean; lane = output channel o (64) ----
    float m0[16], m1[16], m2[16], ag[16];
#pragma unroll
    for (int e = 0; e < 16; ++e) { m0[e] = 0.f; m1[e] = 0.f; m2[e] = 0.f; ag[e] = 0.f; }

    for (int oct = 0; oct < 8; ++oct) {
      uint4 t0 = *(const uint4*)&theta_s[(0 * 64 + l) * 36 + oct * 4];
      uint4 t1 = *(const uint4*)&theta_s[(1 * 64 + l) * 36 + oct * 4];
      uint4 t2 = *(const uint4*)&theta_s[(2 * 64 + l) * 36 + oct * 4];
      float w0f[8], w1f[8], w2f[8];
      unpack8(t0, w0f);
      unpack8(t1, w1f);
      unpack8(t2, w2f);
#pragma unroll
      for (int j = 0; j < 8; ++j) {
        const float4* nr = (const float4*)&nb_s[wv][oct * 8 + j][0];
        float4 p0 = nr[0], p1 = nr[1], p2 = nr[2], p3 = nr[3];
        float xv[16] = {p0.x, p0.y, p0.z, p0.w, p1.x, p1.y, p1.z, p1.w,
                        p2.x, p2.y, p2.z, p2.w, p3.x, p3.y, p3.z, p3.w};
#pragma unroll
        for (int e = 0; e < 16; ++e) {
          m0[e] = fmaf(w0f[j], xv[e], m0[e]);
          m1[e] = fmaf(w1f[j], xv[e], m1[e]);
          m2[e] = fmaf(w2f[j], xv[e], m2[e]);
        }
      }
    }
    for (int oct = 0; oct < 4; ++oct) {
      float4 g0 = *(const float4*)&gateW_s[l * 36 + oct * 8];
      float4 g1 = *(const float4*)&gateW_s[l * 36 + oct * 8 + 4];
      float wg[8] = {g0.x, g0.y, g0.z, g0.w, g1.x, g1.y, g1.z, g1.w};
#pragma unroll
      for (int j = 0; j < 8; ++j) {
        const float4* fr = (const float4*)&wf1_s[wv][oct * 8 + j][0];
        float4 p0 = fr[0], p1 = fr[1], p2 = fr[2], p3 = fr[3];
        float xv[16] = {p0.x, p0.y, p0.z, p0.w, p1.x, p1.y, p1.z, p1.w,
                        p2.x, p2.y, p2.z, p2.w, p3.x, p3.y, p3.z, p3.w};
#pragma unroll
        for (int e = 0; e < 16; ++e) ag[e] = fmaf(wg[j], xv[e], ag[e]);
      }
    }
    // select per-edge theta result, add theta_b, sigmoid gate, mean over k
    float macc = 0.f;
#pragma unroll
    for (int e = 0; e < 16; ++e) {
      int et  = et_s[wv][e];
      float m = m0[e];
      m = (et == 1) ? m1[e] : m;
      m = (et == 2) ? m2[e] : m;
      m += theta_b_s[et * 64 + l];
      float g = 1.f / (1.f + __expf(-(ag[e] + gbr)));
      macc = fmaf(m, g, macc);
    }
    float no = fmaxf(macc * 0.0625f, 0.f);
    nout_s[wv][l] = no;

    // ---- nf2 = relu(bn(nW2 @ n_out)) + node residual; lane = o2 ----
    {
      float accA = 0.f, accB = 0.f;
      for (int oct = 0; oct < 8; ++oct) {
        uint4 wq = *(const uint4*)&nW2_s[l * 36 + oct * 4];
        float wf[8];
        unpack8(wq, wf);
        const float4* xr = (const float4*)&nout_s[wv][oct * 8];
        float4 p0 = xr[0], p1 = xr[1];
        float xv[8] = {p0.x, p0.y, p0.z, p0.w, p1.x, p1.y, p1.z, p1.w};
#pragma unroll
        for (int j = 0; j < 8; ++j) {
          if (j & 1) accB = fmaf(wf[j], xv[j], accB);
          else       accA = fmaf(wf[j], xv[j], accA);
        }
      }
      float y = fmaxf(fmaf(ns2r, (accA + accB) + nb2r, nsh2r), 0.f);
      size_t off = (size_t)(b * 64 + l) * N_ + n;
      out_nf[off] = y + node[off];
    }

    // ---- w_out = relu(edgeW @ [wf1; nb]); stored into x_s (x tile is dead) ----
    {
      float acc[8] = {0, 0, 0, 0, 0, 0, 0, 0};
      for (int oct = 0; oct < 4; ++oct) {  // cat channels 0..31 (wf1)
        float4 e0 = *(const float4*)&edgeW_s[o32 * 100 + oct * 8];
        float4 e1 = *(const float4*)&edgeW_s[o32 * 100 + oct * 8 + 4];
        float we[8] = {e0.x, e0.y, e0.z, e0.w, e1.x, e1.y, e1.z, e1.w};
#pragma unroll
        for (int j = 0; j < 8; ++j) {
          const float4* fr = (const float4*)&wf1_s[wv][oct * 8 + j][eh * 8];
          float4 p0 = fr[0], p1 = fr[1];
          float xv[8] = {p0.x, p0.y, p0.z, p0.w, p1.x, p1.y, p1.z, p1.w};
#pragma unroll
          for (int e = 0; e < 8; ++e) acc[e] = fmaf(we[j], xv[e], acc[e]);
        }
      }
      for (int oct = 0; oct < 8; ++oct) {  // cat channels 32..95 (nb)
        float4 e0 = *(const float4*)&edgeW_s[o32 * 100 + 32 + oct * 8];
        float4 e1 = *(const float4*)&edgeW_s[o32 * 100 + 32 + oct * 8 + 4];
        float we[8] = {e0.x, e0.y, e0.z, e0.w, e1.x, e1.y, e1.z, e1.w};
#pragma unroll
        for (int j = 0; j < 8; ++j) {
          const float4* nr = (const float4*)&nb_s[wv][oct * 8 + j][eh * 8];
          float4 p0 = nr[0], p1 = nr[1];
          float xv[8] = {p0.x, p0.y, p0.z, p0.w, p1.x, p1.y, p1.z, p1.w};
#pragma unroll
          for (int e = 0; e < 8; ++e) acc[e] = fmaf(we[j], xv[e], acc[e]);
        }
      }
      float wo[8];
#pragma unroll
      for (int e = 0; e < 8; ++e) wo[e] = fmaxf(acc[e] + ebr, 0.f);
      float4 q0 = {wo[0], wo[1], wo[2], wo[3]};
      float4 q1 = {wo[4], wo[5], wo[6], wo[7]};
      *(float4*)&x_s[wv][o32][eh * 8]     = q0;
      *(float4*)&x_s[wv][o32][eh * 8 + 4] = q1;
    }

    // ---- wf2 = relu(bn(wW2 @ w_out)) + wfeat residual; store ----
    {
      float acc[8] = {0, 0, 0, 0, 0, 0, 0, 0};
      for (int oct = 0; oct < 4; ++oct) {
        uint4 wq = *(const uint4*)&wW2_s[o32 * 20 + oct * 4];
        float wf[8];
        unpack8(wq, wf);
#pragma unroll
        for (int j = 0; j < 8; ++j) {
          const float4* xr = (const float4*)&x_s[wv][oct * 8 + j][eh * 8];
          float4 p0 = xr[0], p1 = xr[1];
          float xv[8] = {p0.x, p0.y, p0.z, p0.w, p1.x, p1.y, p1.z, p1.w};
#pragma unroll
          for (int e = 0; e < 8; ++e) acc[e] = fmaf(wf[j], xv[e], acc[e]);
        }
      }
      size_t base = ((size_t)(b * 32 + o32) * N_ + n) * 16 + eh * 8;
      float4 r0 = *(const float4*)&wfeat[base];
      float4 r1 = *(const float4*)&wfeat[base + 4];
      float4 v0, v1;
      v0.x = fmaxf(fmaf(ws2r, acc[0] + wb2r, wsh2r), 0.f) + r0.x;
      v0.y = fmaxf(fmaf(ws2r, acc[1] + wb2r, wsh2r), 0.f) + r0.y;
      v0.z = fmaxf(fmaf(ws2r, acc[2] + wb2r, wsh2r), 0.f) + r0.z;
      v0.w = fmaxf(fmaf(ws2r, acc[3] + wb2r, wsh2r), 0.f) + r0.w;
      v1.x = fmaxf(fmaf(ws2r, acc[4] + wb2r, wsh2r), 0.f) + r1.x;
      v1.y = fmaxf(fmaf(ws2r, acc[5] + wb2r, wsh2r), 0.f) + r1.y;
      v1.z = fmaxf(fmaf(ws2r, acc[6] + wb2r, wsh2r), 0.f) + r1.z;
      v1.w = fmaxf(fmaf(ws2r, acc[7] + wb2r, wsh2r), 0.f) + r1.w;
      *(float4*)&out_wf[base]     = v0;
      *(float4*)&out_wf[base + 4] = v1;
    }
  }
}

extern "C" void kernel_launch(void* const* d_in, const int* in_sizes, int n_in,
                              void* d_out, int out_size, void* d_ws, size_t ws_size,
                              hipStream_t stream) {
  const float* node    = (const float*)d_in[0];
  const float* wfeat   = (const float*)d_in[1];
  const int*   etype   = (const int*)d_in[2];
  const int*   nn_idx  = (const int*)d_in[3];
  const float* nW1     = (const float*)d_in[4];
  const float* nb1     = (const float*)d_in[5];
  const float* ns1     = (const float*)d_in[6];
  const float* nsh1    = (const float*)d_in[7];
  const float* wW1     = (const float*)d_in[8];
  const float* wb1     = (const float*)d_in[9];
  const float* ws1     = (const float*)d_in[10];
  const float* wsh1    = (const float*)d_in[11];
  const float* theta   = (const float*)d_in[12];
  const float* theta_b = (const float*)d_in[13];
  const float* gateW   = (const float*)d_in[14];
  const float* gate_b  = (const float*)d_in[15];
  const float* edgeW   = (const float*)d_in[16];
  const float* edge_b  = (const float*)d_in[17];
  const float* nW2     = (const float*)d_in[18];
  const float* nb2     = (const float*)d_in[19];
  const float* ns2     = (const float*)d_in[20];
  const float* nsh2    = (const float*)d_in[21];
  const float* wW2     = (const float*)d_in[22];
  const float* wb2     = (const float*)d_in[23];
  const float* ws2     = (const float*)d_in[24];
  const float* wsh2    = (const float*)d_in[25];

  float* nf1    = (float*)d_ws;                       // B*N*64 f32 = 10.24 MB
  float* out_nf = (float*)d_out;                      // (B,64,N,1)
  float* out_wf = (float*)d_out + (size_t)B_ * 64 * N_;  // (B,32,N,16)

  k_nf1<<<2500, 256, 0, stream>>>(node, nW1, nb1, ns1, nsh1, nf1);
  k_fused<<<1250, 512, 0, stream>>>(node, wfeat, etype, nn_idx, nf1,
                                    wW1, wb1, ws1, wsh1,
                                    theta, theta_b, gateW, gate_b, edgeW, edge_b,
                                    nW2, nb2, ns2, nsh2, wW2, wb2, ws2, wsh2,
                                    out_nf, out_wf);
}